// Round 6
// baseline (72.421 us; speedup 1.0000x reference)
//
#include <hip/hip_runtime.h>
#include <hip/hip_fp16.h>

#define Bdim 4
#define Cdim 128
#define Hdim 96
#define Wdim 96
#define HW   (Hdim*Wdim)        // 9216
#define NOC  18                 // rot conv output channels
#define PADH 98                 // fp32 pad rows: true r -> r+1
#define PADW 104                // fp32 pad cols: true c -> c+3 (16B-aligned rows)

typedef __attribute__((ext_vector_type(8))) short bf16x8;
typedef __attribute__((ext_vector_type(4))) float f32x4;

__device__ inline short f2bf(float f) {          // round-to-nearest-even bf16
    unsigned u = __float_as_uint(f);
    unsigned r = (u + 0x7FFFu + ((u >> 16) & 1u)) >> 16;
    return (short)r;
}

// ---------------------------------------------------------------------------
// Kernel 1 (prep): one fused kernel, 5 block roles.
//  [0,768)     interior: LDS-transpose 64c x 96w -> bf16 NHWC xnh + fp32 xpad.
//  [768,776)   zero xnh halo rows r=0,97.
//  [776,784)   zero xnh halo cols w=0,97 (rows 1..96).   <-- was missing in R5
//  [784,928)   repack rot_w -> wpk A-fragments (oc>=18 zero).
//  [928,1440)  zero fp32 xpad borders.
// ---------------------------------------------------------------------------
__global__ __launch_bounds__(256) void prep_kernel(const float* __restrict__ x,
                                                   const float* __restrict__ rot_w,
                                                   float* __restrict__ xpad,
                                                   short* __restrict__ xnh,
                                                   short* __restrict__ wpk) {
    __shared__ short ldsT[96 * 72];   // [w][c_local], stride 72
    const int bid = blockIdx.x;
    const int t   = threadIdx.x;

    if (bid < 768) {
        int b = bid / 192;
        int h = (bid / 2) % 96;
        int chalf = bid & 1;
        int c0 = chalf * 64;
        const float* xs = x + ((size_t)(b * Cdim + c0) * Hdim + h) * Wdim;
        float* xf = xpad + ((size_t)(b * Cdim + c0) * PADH + (h + 1)) * PADW + 3;
#pragma unroll
        for (int i = 0; i < 24; ++i) {
            int idx = i * 256 + t;           // 0..6143 = 64c x 96w
            int w  = idx % 96;
            int ci = idx / 96;
            float v = xs[(size_t)ci * HW + w];
            ldsT[w * 72 + ci] = f2bf(v);
            xf[(size_t)ci * (PADH * PADW) + w] = v;
        }
        __syncthreads();
        short* dst = xnh + (((size_t)b * 98 + (h + 1)) * 98 + 1) * 128 + c0;
#pragma unroll
        for (int j = 0; j < 3; ++j) {
            int idx = j * 256 + t;           // 0..767 = 96w x 8 c-groups
            int c8 = idx % 8;
            int w  = idx / 8;
            bf16x8 v = *(const bf16x8*)&ldsT[w * 72 + c8 * 8];
            *(bf16x8*)(dst + (size_t)w * 128 + c8 * 8) = v;
        }
    } else if (bid < 776) {
        int z = bid - 768;
        int b = z / 2;
        int r = (z & 1) ? 97 : 0;
        short* base = xnh + ((size_t)b * 98 + r) * 98 * 128;
        bf16x8 zero = {0,0,0,0,0,0,0,0};
        for (int i = t; i < 1568; i += 256)      // 1568*8 = 98*128
            ((bf16x8*)base)[i] = zero;
    } else if (bid < 784) {
        int z = bid - 776;
        int b = z / 2;
        int col = (z & 1) ? 97 : 0;
        bf16x8 zero = {0,0,0,0,0,0,0,0};
        for (int i = t; i < 1536; i += 256) {    // rows 1..96 x 16 c-groups
            int r  = 1 + i / 16;
            int c8 = i % 16;
            *(bf16x8*)(xnh + (((size_t)b * 98 + r) * 98 + col) * 128 + c8 * 8) = zero;
        }
    } else if (bid < 928) {
        int f = (bid - 784) * 256 + t;           // 0..36863
        int e    = f & 7;
        int l    = (f >> 3) & 63;
        int ch   = (f >> 9) & 3;
        int tap  = (f >> 11) % 9;
        int mt   = f / 18432;
        int oc = mt * 16 + (l & 15);
        int c  = ch * 32 + (l >> 4) * 8 + e;
        float v = (oc < NOC) ? rot_w[(size_t)oc * (Cdim * 9) + c * 9 + tap] : 0.f;
        wpk[f] = f2bf(v);
    } else {
        int bi = bid - 928;                      // 0..511 -> (b,c)
        float* base = xpad + (size_t)bi * PADH * PADW;
        for (int i = t; i < 976; i += 256) {
            int r, col;
            if (i < 208) { r = (i / 104) * 97; col = i % 104; }
            else {
                int j = i - 208;
                r = 1 + j / 8;
                int k8 = j % 8;
                col = (k8 < 3) ? k8 : 96 + k8;   // cols 0,1,2,99..103
            }
            base[r * PADW + col] = 0.f;
        }
    }
}

// ---------------------------------------------------------------------------
// Kernel 2: conv (bf16 MFMA implicit GEMM) with FUSED coef epilogue.
// Wave = 16 pixels x 32 oc-rows. 2-stage software pipeline; all A/B offsets
// are compile-time immediates. 4 independent MFMA chains.
// Epilogue: per-wave D-transpose through LDS scratch (no barrier), compute
// bilinear coefficient quads, store coefq[(b*9+t)*HW+hw] float4.
// ---------------------------------------------------------------------------
__global__ __launch_bounds__(256, 2) void conv_mfma(const short* __restrict__ xnh,
                                                    const short* __restrict__ wpk,
                                                    const float* __restrict__ rot_b,
                                                    float4* __restrict__ coefq) {
    __shared__ short wlds[36864];                // 72 KB A-fragments
    __shared__ float dsc[64 * 20];               // 5 KB per-wave D scratch
    const int tid  = threadIdx.x;
    const int lane = tid & 63;
    const int wid  = tid >> 6;
    for (int i = tid; i < 4608; i += 256)
        ((bf16x8*)wlds)[i] = ((const bf16x8*)wpk)[i];
    __syncthreads();

    const int ntile = blockIdx.x * 4 + wid;      // 0..2303
    const int b   = ntile / 576;
    const int hw0 = (ntile % 576) * 16;
    const int h   = hw0 / Wdim;
    const int w0  = hw0 % Wdim;
    const int px = lane & 15, kg = lane >> 4;

    f32x4 a00 = {0,0,0,0}, a01 = {0,0,0,0};      // mt0: ch{0,1}, ch{2,3}
    f32x4 a10 = {0,0,0,0}, a11 = {0,0,0,0};      // mt1
    const short* xb = xnh + (((size_t)b * 98 + h) * 98 + (w0 + px)) * 128 + kg * 8;
    const short* wl = wlds + lane * 8;

    bf16x8 Bc[4], A0c[4], A1c[4];
#pragma unroll
    for (int ch = 0; ch < 4; ++ch) {             // preload tap 0
        Bc[ch]  = *(const bf16x8*)(xb + ch * 32);
        A0c[ch] = *(const bf16x8*)(wl + ch * 512);
        A1c[ch] = *(const bf16x8*)(wl + (36 + ch) * 512);
    }

#pragma unroll
    for (int tap = 0; tap < 9; ++tap) {
        bf16x8 Bn[4], A0n[4], A1n[4];
        if (tap < 8) {
            const int di = (tap + 1) / 3, dj = (tap + 1) % 3;
            const short* xr = xb + (di * 98 + dj) * 128;
#pragma unroll
            for (int ch = 0; ch < 4; ++ch) {
                Bn[ch]  = *(const bf16x8*)(xr + ch * 32);
                A0n[ch] = *(const bf16x8*)(wl + ((tap + 1) * 4 + ch) * 512);
                A1n[ch] = *(const bf16x8*)(wl + ((9 + tap + 1) * 4 + ch) * 512);
            }
        }
        a00 = __builtin_amdgcn_mfma_f32_16x16x32_bf16(A0c[0], Bc[0], a00, 0, 0, 0);
        a10 = __builtin_amdgcn_mfma_f32_16x16x32_bf16(A1c[0], Bc[0], a10, 0, 0, 0);
        a01 = __builtin_amdgcn_mfma_f32_16x16x32_bf16(A0c[1], Bc[1], a01, 0, 0, 0);
        a11 = __builtin_amdgcn_mfma_f32_16x16x32_bf16(A1c[1], Bc[1], a11, 0, 0, 0);
        a00 = __builtin_amdgcn_mfma_f32_16x16x32_bf16(A0c[2], Bc[2], a00, 0, 0, 0);
        a10 = __builtin_amdgcn_mfma_f32_16x16x32_bf16(A1c[2], Bc[2], a10, 0, 0, 0);
        a01 = __builtin_amdgcn_mfma_f32_16x16x32_bf16(A0c[3], Bc[3], a01, 0, 0, 0);
        a11 = __builtin_amdgcn_mfma_f32_16x16x32_bf16(A1c[3], Bc[3], a11, 0, 0, 0);
        if (tap < 8) {
#pragma unroll
            for (int ch = 0; ch < 4; ++ch) { Bc[ch] = Bn[ch]; A0c[ch] = A0n[ch]; A1c[ch] = A1n[ch]; }
        }
    }
    f32x4 acc0 = a00 + a01;
    f32x4 acc1 = a10 + a11;

    // ---- fused coef epilogue (per-wave, no barrier) ----
    // D layout: col = lane&15 = pixel, row = kg*4 + reg = oc.
    float* ds = dsc + (wid * 16) * 20;
    *(f32x4*)(ds + px * 20 + kg * 4) = acc0;     // 16B-aligned (80B row stride)
    if (kg == 0) {
        ds[px * 20 + 16] = acc1[0];
        ds[px * 20 + 17] = acc1[1];
    }
    __builtin_amdgcn_wave_barrier();             // ordering hint only (same wave)

    const int px2 = lane & 15, tq = lane >> 4;
    if (tq < 3) {
        const float* dr = ds + px2 * 20;
        const int hwp = hw0 + px2;
#pragma unroll
        for (int k = 0; k < 3; ++k) {
            int tt = tq * 3 + k;
            int i = tt / 3, j = tt % 3;
            float ch = dr[2 * tt]     + rot_b[2 * tt]     + (0.5f + (float)i);
            float cw = dr[2 * tt + 1] + rot_b[2 * tt + 1] + (0.5f + (float)j);
            ch = fminf(fmaxf(ch, 0.f), 3.f);
            cw = fminf(fmaxf(cw, 0.f), 3.f);
            float h0f = floorf(ch), w0f = floorf(cw);
            float lh = ch - h0f, lw = cw - w0f;
            int h0 = (int)h0f, w0i = (int)w0f;
            float bh0 = 1.f - lh;
            float aw0 = 1.f - lw;
            if (h0 >= 3)  { h0 = 2;  bh0 = 0.f; }
            if (w0i >= 3) { w0i = 2; aw0 = 0.f; }
            float4 cf;
            cf.x = aw0 * bh0;
            cf.y = (1.f - aw0) * bh0;
            cf.z = aw0 * (1.f - bh0);
            cf.w = (float)(h0 * 3 + w0i);
            coefq[(size_t)(b * 9 + tt) * HW + hwp] = cf;
        }
    }
}

// ---------------------------------------------------------------------------
// Kernel 3: apply. Thread = 1 pixel, loops 32 channels (ty picks c-range).
// Table packed fp16 ushort4 (8B): ds_read_b64 + v_cvt_f32_f16 unpack.
// q's stay fp32 and sum to 1 -> table error <= |W|*2^-11.
// ---------------------------------------------------------------------------
__global__ __launch_bounds__(256) void apply_kernel(const float* __restrict__ xpad,
                                                    const float4* __restrict__ coefq,
                                                    const float* __restrict__ weight,
                                                    float* __restrict__ out) {
    __shared__ ushort4 wq[Cdim * 9];             // 9216 B
    int tid = threadIdx.y * 64 + threadIdx.x;
    for (int i = tid; i < Cdim * 9; i += 256) {
        int c = i / 9, t = i - c * 9;
        int r = t / 3, s = t - r * 3;
        const float* wb = weight + (size_t)c * 16 + r * 4 + s;
        ushort4 u;
        u.x = __half_as_ushort(__float2half(wb[0]));
        u.y = __half_as_ushort(__float2half(wb[1]));
        u.z = __half_as_ushort(__float2half(wb[4]));
        u.w = __half_as_ushort(__float2half(wb[5]));
        wq[i] = u;
    }
    __syncthreads();

    int px = blockIdx.x * 64 + threadIdx.x;   // 0..36863
    int b  = px / HW;
    int hw = px % HW;
    int h  = hw / Wdim;
    int wc = hw % Wdim;

    float q00[9], q01[9], q10[9], q11[9];
    int lidx[9];
#pragma unroll
    for (int t = 0; t < 9; ++t) {
        float4 cf = coefq[(size_t)(b * 9 + t) * HW + hw];
        q00[t] = cf.x;
        q01[t] = cf.y;
        q10[t] = cf.z;
        q11[t] = 1.f - cf.x - cf.y - cf.z;
        lidx[t] = (int)cf.w;
    }

    int c0 = threadIdx.y * 32;
    const float* xb = xpad + ((size_t)(b * Cdim + c0) * PADH + h) * PADW + (wc + 2);
    float* ob = out + ((size_t)(b * Cdim + c0)) * HW + hw;

#pragma unroll 2
    for (int k = 0; k < 32; ++k) {
        int c = c0 + k;
        float acc = 0.f;
#pragma unroll
        for (int t = 0; t < 9; ++t) {
            ushort4 u = wq[c * 9 + lidx[t]];
            float g0 = __half2float(__ushort_as_half(u.x));
            float g1 = __half2float(__ushort_as_half(u.y));
            float g2 = __half2float(__ushort_as_half(u.z));
            float g3 = __half2float(__ushort_as_half(u.w));
            float ws = q00[t] * g0;
            ws = fmaf(q01[t], g1, ws);
            ws = fmaf(q10[t], g2, ws);
            ws = fmaf(q11[t], g3, ws);
            acc = fmaf(ws, xb[(t / 3) * PADW + (t % 3)], acc);
        }
        ob[(size_t)k * HW] = acc;
        xb += (size_t)PADH * PADW;
    }
}

// ---------------------------------------------------------------------------
extern "C" void kernel_launch(void* const* d_in, const int* in_sizes, int n_in,
                              void* d_out, int out_size, void* d_ws, size_t ws_size,
                              hipStream_t stream) {
    const float* x      = (const float*)d_in[0];
    const float* rot_w  = (const float*)d_in[1];
    const float* rot_b  = (const float*)d_in[2];
    const float* weight = (const float*)d_in[3];
    float* out = (float*)d_out;

    char* ws = (char*)d_ws;
    const size_t xpad_bytes = (size_t)Bdim * Cdim * PADH * PADW * 4;   // 20,873,216
    const size_t xnh_bytes  = (size_t)Bdim * 98 * 98 * 128 * 2;        //  9,834,496
    const size_t wpk_bytes  = (size_t)2 * 9 * 4 * 64 * 8 * 2;          //     73,728

    float*  xpad  = (float*)ws;
    short*  xnh   = (short*)(ws + xpad_bytes);
    short*  wpk   = (short*)(ws + xpad_bytes + xnh_bytes);
    float4* coefq = (float4*)(ws + xpad_bytes + xnh_bytes + wpk_bytes);

    prep_kernel<<<1440, 256, 0, stream>>>(x, rot_w, xpad, xnh, wpk);
    conv_mfma<<<576, 256, 0, stream>>>(xnh, wpk, rot_b, coefq);
    apply_kernel<<<dim3(Bdim * HW / 64), dim3(64, 4), 0, stream>>>(xpad, coefq, weight, out);
}

// Round 7
// 59.320 us; speedup vs baseline: 1.2209x; 1.2209x over previous
//
#include <hip/hip_runtime.h>
#include <hip/hip_fp16.h>

#define Bdim 4
#define Cdim 128
#define Hdim 96
#define Wdim 96
#define HW   (Hdim*Wdim)        // 9216
#define NOC  18                 // rot conv output channels

typedef __attribute__((ext_vector_type(8))) short bf16x8;
typedef __attribute__((ext_vector_type(4))) float f32x4;

__device__ inline short f2bf(float f) {          // round-to-nearest-even bf16
    unsigned u = __float_as_uint(f);
    unsigned r = (u + 0x7FFFu + ((u >> 16) & 1u)) >> 16;
    return (short)r;
}

__device__ inline void unpack8(uint4 u, float* f) {   // 8 bf16 -> 8 f32 (1 VALU each)
    f[0] = __uint_as_float(u.x << 16); f[1] = __uint_as_float(u.x & 0xFFFF0000u);
    f[2] = __uint_as_float(u.y << 16); f[3] = __uint_as_float(u.y & 0xFFFF0000u);
    f[4] = __uint_as_float(u.z << 16); f[5] = __uint_as_float(u.z & 0xFFFF0000u);
    f[6] = __uint_as_float(u.w << 16); f[7] = __uint_as_float(u.w & 0xFFFF0000u);
}

// ---------------------------------------------------------------------------
// Kernel 1 (prep): x -> bf16 NHWC xnh (halo-padded) + wpk A-fragments.
//  [0,768)    interior: LDS-transpose 64c x 96w -> xnh[b][h+1][w+1][c].
//  [768,776)  zero xnh halo rows r=0,97.
//  [776,784)  zero xnh halo cols w=0,97 (rows 1..96).
//  [784,928)  repack rot_w -> wpk[mt][tap][chunk][lane][8] (oc>=18 zero).
// ---------------------------------------------------------------------------
__global__ __launch_bounds__(256) void prep_kernel(const float* __restrict__ x,
                                                   const float* __restrict__ rot_w,
                                                   short* __restrict__ xnh,
                                                   short* __restrict__ wpk) {
    __shared__ short ldsT[96 * 72];   // [w][c_local], stride 72
    const int bid = blockIdx.x;
    const int t   = threadIdx.x;

    if (bid < 768) {
        int b = bid / 192;
        int h = (bid / 2) % 96;
        int c0 = (bid & 1) * 64;
        const float* xs = x + ((size_t)(b * Cdim + c0) * Hdim + h) * Wdim;
#pragma unroll
        for (int i = 0; i < 24; ++i) {
            int idx = i * 256 + t;           // 0..6143 = 64c x 96w
            int w  = idx % 96;
            int ci = idx / 96;
            ldsT[w * 72 + ci] = f2bf(xs[(size_t)ci * HW + w]);
        }
        __syncthreads();
        short* dst = xnh + (((size_t)b * 98 + (h + 1)) * 98 + 1) * 128 + c0;
#pragma unroll
        for (int j = 0; j < 3; ++j) {
            int idx = j * 256 + t;           // 0..767 = 96w x 8 c-groups
            int c8 = idx % 8;
            int w  = idx / 8;
            *(bf16x8*)(dst + (size_t)w * 128 + c8 * 8) = *(const bf16x8*)&ldsT[w * 72 + c8 * 8];
        }
    } else if (bid < 776) {
        int z = bid - 768;
        int b = z / 2;
        int r = (z & 1) ? 97 : 0;
        short* base = xnh + ((size_t)b * 98 + r) * 98 * 128;
        bf16x8 zero = {0,0,0,0,0,0,0,0};
        for (int i = t; i < 1568; i += 256)      // 1568*8 = 98*128
            ((bf16x8*)base)[i] = zero;
    } else if (bid < 784) {
        int z = bid - 776;
        int b = z / 2;
        int col = (z & 1) ? 97 : 0;
        bf16x8 zero = {0,0,0,0,0,0,0,0};
        for (int i = t; i < 1536; i += 256) {    // rows 1..96 x 16 c-groups
            int r  = 1 + i / 16;
            int c8 = i % 16;
            *(bf16x8*)(xnh + (((size_t)b * 98 + r) * 98 + col) * 128 + c8 * 8) = zero;
        }
    } else {
        int f = (bid - 784) * 256 + t;           // 0..36863
        int e    = f & 7;
        int l    = (f >> 3) & 63;
        int ch   = (f >> 9) & 3;
        int tap  = (f >> 11) % 9;
        int mt   = f / 18432;
        int oc = mt * 16 + (l & 15);
        int c  = ch * 32 + (l >> 4) * 8 + e;
        float v = (oc < NOC) ? rot_w[(size_t)oc * (Cdim * 9) + c * 9 + tap] : 0.f;
        wpk[f] = f2bf(v);
    }
}

// ---------------------------------------------------------------------------
// Kernel 2: conv (bf16 MFMA implicit GEMM) with FUSED coef epilogue.
// IDENTICAL to R6 (kept as control for dur attribution).
// ---------------------------------------------------------------------------
__global__ __launch_bounds__(256, 2) void conv_mfma(const short* __restrict__ xnh,
                                                    const short* __restrict__ wpk,
                                                    const float* __restrict__ rot_b,
                                                    float4* __restrict__ coefq) {
    __shared__ short wlds[36864];                // 72 KB A-fragments
    __shared__ float dsc[64 * 20];               // 5 KB per-wave D scratch
    const int tid  = threadIdx.x;
    const int lane = tid & 63;
    const int wid  = tid >> 6;
    for (int i = tid; i < 4608; i += 256)
        ((bf16x8*)wlds)[i] = ((const bf16x8*)wpk)[i];
    __syncthreads();

    const int ntile = blockIdx.x * 4 + wid;      // 0..2303
    const int b   = ntile / 576;
    const int hw0 = (ntile % 576) * 16;
    const int h   = hw0 / Wdim;
    const int w0  = hw0 % Wdim;
    const int px = lane & 15, kg = lane >> 4;

    f32x4 a00 = {0,0,0,0}, a01 = {0,0,0,0};
    f32x4 a10 = {0,0,0,0}, a11 = {0,0,0,0};
    const short* xb = xnh + (((size_t)b * 98 + h) * 98 + (w0 + px)) * 128 + kg * 8;
    const short* wl = wlds + lane * 8;

    bf16x8 Bc[4], A0c[4], A1c[4];
#pragma unroll
    for (int ch = 0; ch < 4; ++ch) {             // preload tap 0
        Bc[ch]  = *(const bf16x8*)(xb + ch * 32);
        A0c[ch] = *(const bf16x8*)(wl + ch * 512);
        A1c[ch] = *(const bf16x8*)(wl + (36 + ch) * 512);
    }

#pragma unroll
    for (int tap = 0; tap < 9; ++tap) {
        bf16x8 Bn[4], A0n[4], A1n[4];
        if (tap < 8) {
            const int di = (tap + 1) / 3, dj = (tap + 1) % 3;
            const short* xr = xb + (di * 98 + dj) * 128;
#pragma unroll
            for (int ch = 0; ch < 4; ++ch) {
                Bn[ch]  = *(const bf16x8*)(xr + ch * 32);
                A0n[ch] = *(const bf16x8*)(wl + ((tap + 1) * 4 + ch) * 512);
                A1n[ch] = *(const bf16x8*)(wl + ((9 + tap + 1) * 4 + ch) * 512);
            }
        }
        a00 = __builtin_amdgcn_mfma_f32_16x16x32_bf16(A0c[0], Bc[0], a00, 0, 0, 0);
        a10 = __builtin_amdgcn_mfma_f32_16x16x32_bf16(A1c[0], Bc[0], a10, 0, 0, 0);
        a01 = __builtin_amdgcn_mfma_f32_16x16x32_bf16(A0c[1], Bc[1], a01, 0, 0, 0);
        a11 = __builtin_amdgcn_mfma_f32_16x16x32_bf16(A1c[1], Bc[1], a11, 0, 0, 0);
        a00 = __builtin_amdgcn_mfma_f32_16x16x32_bf16(A0c[2], Bc[2], a00, 0, 0, 0);
        a10 = __builtin_amdgcn_mfma_f32_16x16x32_bf16(A1c[2], Bc[2], a10, 0, 0, 0);
        a01 = __builtin_amdgcn_mfma_f32_16x16x32_bf16(A0c[3], Bc[3], a01, 0, 0, 0);
        a11 = __builtin_amdgcn_mfma_f32_16x16x32_bf16(A1c[3], Bc[3], a11, 0, 0, 0);
        if (tap < 8) {
#pragma unroll
            for (int ch = 0; ch < 4; ++ch) { Bc[ch] = Bn[ch]; A0c[ch] = A0n[ch]; A1c[ch] = A1n[ch]; }
        }
    }
    f32x4 acc0 = a00 + a01;
    f32x4 acc1 = a10 + a11;

    // ---- fused coef epilogue (per-wave, no barrier) ----
    float* ds = dsc + (wid * 16) * 20;
    *(f32x4*)(ds + px * 20 + kg * 4) = acc0;
    if (kg == 0) {
        ds[px * 20 + 16] = acc1[0];
        ds[px * 20 + 17] = acc1[1];
    }
    __builtin_amdgcn_wave_barrier();

    const int px2 = lane & 15, tq = lane >> 4;
    if (tq < 3) {
        const float* dr = ds + px2 * 20;
        const int hwp = hw0 + px2;
#pragma unroll
        for (int k = 0; k < 3; ++k) {
            int tt = tq * 3 + k;
            int i = tt / 3, j = tt % 3;
            float ch = dr[2 * tt]     + rot_b[2 * tt]     + (0.5f + (float)i);
            float cw = dr[2 * tt + 1] + rot_b[2 * tt + 1] + (0.5f + (float)j);
            ch = fminf(fmaxf(ch, 0.f), 3.f);
            cw = fminf(fmaxf(cw, 0.f), 3.f);
            float h0f = floorf(ch), w0f = floorf(cw);
            float lh = ch - h0f, lw = cw - w0f;
            int h0 = (int)h0f, w0i = (int)w0f;
            float bh0 = 1.f - lh;
            float aw0 = 1.f - lw;
            if (h0 >= 3)  { h0 = 2;  bh0 = 0.f; }
            if (w0i >= 3) { w0i = 2; aw0 = 0.f; }
            float4 cf;
            cf.x = aw0 * bh0;
            cf.y = (1.f - aw0) * bh0;
            cf.z = aw0 * (1.f - bh0);
            cf.w = (float)(h0 * 3 + w0i);
            coefq[(size_t)(b * 9 + tt) * HW + hwp] = cf;
        }
    }
}

// ---------------------------------------------------------------------------
// Kernel 3: apply from bf16 NHWC. Thread = 1 pixel x 32 channels (ty).
// Per tap: 4x dwordx4 loads (64B = 32 bf16 channels), unpack 1 VALU/value.
// Table fp16 ushort4 (8B ds_read_b64), q's fp32.
// ---------------------------------------------------------------------------
__global__ __launch_bounds__(256) void apply_kernel(const short* __restrict__ xnh,
                                                    const float4* __restrict__ coefq,
                                                    const float* __restrict__ weight,
                                                    float* __restrict__ out) {
    __shared__ ushort4 wq[Cdim * 9];             // 9216 B
    int tid = threadIdx.y * 64 + threadIdx.x;
    for (int i = tid; i < Cdim * 9; i += 256) {
        int c = i / 9, t = i - c * 9;
        int r = t / 3, s = t - r * 3;
        const float* wb = weight + (size_t)c * 16 + r * 4 + s;
        ushort4 u;
        u.x = __half_as_ushort(__float2half(wb[0]));
        u.y = __half_as_ushort(__float2half(wb[1]));
        u.z = __half_as_ushort(__float2half(wb[4]));
        u.w = __half_as_ushort(__float2half(wb[5]));
        wq[i] = u;
    }
    __syncthreads();

    int px = blockIdx.x * 64 + threadIdx.x;   // 0..36863
    int b  = px / HW;
    int hw = px % HW;
    int h  = hw / Wdim;
    int w  = hw % Wdim;

    float q00[9], q01[9], q10[9], q11[9];
    int lidx[9];
#pragma unroll
    for (int t = 0; t < 9; ++t) {
        float4 cf = coefq[(size_t)(b * 9 + t) * HW + hw];
        q00[t] = cf.x;
        q01[t] = cf.y;
        q10[t] = cf.z;
        q11[t] = 1.f - cf.x - cf.y - cf.z;
        lidx[t] = (int)cf.w;
    }

    const int c0 = threadIdx.y * 32;
    // tap (di,dj): true (h+di-1, w+dj-1) -> xnh row h+di, col w+dj
    const short* xb = xnh + (((size_t)b * 98 + h) * 98 + w) * 128 + c0;

    float acc[32];
#pragma unroll
    for (int k = 0; k < 32; ++k) acc[k] = 0.f;

#pragma unroll
    for (int t = 0; t < 9; ++t) {
        const int di = t / 3, dj = t % 3;
        const short* xr = xb + (di * 98 + dj) * 128;
        uint4 u0 = *(const uint4*)(xr);
        uint4 u1 = *(const uint4*)(xr + 8);
        uint4 u2 = *(const uint4*)(xr + 16);
        uint4 u3 = *(const uint4*)(xr + 24);
        float xv[32];
        unpack8(u0, xv + 0);
        unpack8(u1, xv + 8);
        unpack8(u2, xv + 16);
        unpack8(u3, xv + 24);
#pragma unroll
        for (int k = 0; k < 32; ++k) {
            ushort4 g = wq[(c0 + k) * 9 + lidx[t]];
            float ws = q00[t] * __half2float(__ushort_as_half(g.x));
            ws = fmaf(q01[t], __half2float(__ushort_as_half(g.y)), ws);
            ws = fmaf(q10[t], __half2float(__ushort_as_half(g.z)), ws);
            ws = fmaf(q11[t], __half2float(__ushort_as_half(g.w)), ws);
            acc[k] = fmaf(ws, xv[k], acc[k]);
        }
    }

    float* ob = out + ((size_t)(b * Cdim + c0)) * HW + hw;
#pragma unroll
    for (int k = 0; k < 32; ++k)
        ob[(size_t)k * HW] = acc[k];
}

// ---------------------------------------------------------------------------
extern "C" void kernel_launch(void* const* d_in, const int* in_sizes, int n_in,
                              void* d_out, int out_size, void* d_ws, size_t ws_size,
                              hipStream_t stream) {
    const float* x      = (const float*)d_in[0];
    const float* rot_w  = (const float*)d_in[1];
    const float* rot_b  = (const float*)d_in[2];
    const float* weight = (const float*)d_in[3];
    float* out = (float*)d_out;

    char* ws = (char*)d_ws;
    const size_t xnh_bytes = (size_t)Bdim * 98 * 98 * 128 * 2;   // 9,834,496
    const size_t wpk_bytes = (size_t)2 * 9 * 4 * 64 * 8 * 2;     //    73,728

    short*  xnh   = (short*)ws;
    short*  wpk   = (short*)(ws + xnh_bytes);
    float4* coefq = (float4*)(ws + xnh_bytes + wpk_bytes);       // 5,308,416 B

    prep_kernel<<<928, 256, 0, stream>>>(x, rot_w, xnh, wpk);
    conv_mfma<<<576, 256, 0, stream>>>(xnh, wpk, rot_b, coefq);
    apply_kernel<<<dim3(Bdim * HW / 64), dim3(64, 4), 0, stream>>>(xnh, coefq, weight, out);
}

// Round 8
// 57.334 us; speedup vs baseline: 1.2631x; 1.0346x over previous
//
#include <hip/hip_runtime.h>
#include <hip/hip_fp16.h>

#define Bdim 4
#define Cdim 128
#define Hdim 96
#define Wdim 96
#define HW   (Hdim*Wdim)        // 9216
#define NOC  18                 // rot conv output channels

typedef __attribute__((ext_vector_type(8))) short bf16x8;
typedef __attribute__((ext_vector_type(4))) float f32x4;

__device__ inline short f2bf(float f) {          // round-to-nearest-even bf16
    unsigned u = __float_as_uint(f);
    unsigned r = (u + 0x7FFFu + ((u >> 16) & 1u)) >> 16;
    return (short)r;
}

__device__ inline void unpack8(uint4 u, float* f) {   // 8 bf16 -> 8 f32 (1 VALU each)
    f[0] = __uint_as_float(u.x << 16); f[1] = __uint_as_float(u.x & 0xFFFF0000u);
    f[2] = __uint_as_float(u.y << 16); f[3] = __uint_as_float(u.y & 0xFFFF0000u);
    f[4] = __uint_as_float(u.z << 16); f[5] = __uint_as_float(u.z & 0xFFFF0000u);
    f[6] = __uint_as_float(u.w << 16); f[7] = __uint_as_float(u.w & 0xFFFF0000u);
}

// ---------------------------------------------------------------------------
// Kernel 1 (prep): x -> bf16 NHWC xnh (halo-padded) + wpk A-fragments.
// IDENTICAL to R7 (control).
// ---------------------------------------------------------------------------
__global__ __launch_bounds__(256) void prep_kernel(const float* __restrict__ x,
                                                   const float* __restrict__ rot_w,
                                                   short* __restrict__ xnh,
                                                   short* __restrict__ wpk) {
    __shared__ short ldsT[96 * 72];   // [w][c_local], stride 72
    const int bid = blockIdx.x;
    const int t   = threadIdx.x;

    if (bid < 768) {
        int b = bid / 192;
        int h = (bid / 2) % 96;
        int c0 = (bid & 1) * 64;
        const float* xs = x + ((size_t)(b * Cdim + c0) * Hdim + h) * Wdim;
#pragma unroll
        for (int i = 0; i < 24; ++i) {
            int idx = i * 256 + t;           // 0..6143 = 64c x 96w
            int w  = idx % 96;
            int ci = idx / 96;
            ldsT[w * 72 + ci] = f2bf(xs[(size_t)ci * HW + w]);
        }
        __syncthreads();
        short* dst = xnh + (((size_t)b * 98 + (h + 1)) * 98 + 1) * 128 + c0;
#pragma unroll
        for (int j = 0; j < 3; ++j) {
            int idx = j * 256 + t;           // 0..767 = 96w x 8 c-groups
            int c8 = idx % 8;
            int w  = idx / 8;
            *(bf16x8*)(dst + (size_t)w * 128 + c8 * 8) = *(const bf16x8*)&ldsT[w * 72 + c8 * 8];
        }
    } else if (bid < 776) {
        int z = bid - 768;
        int b = z / 2;
        int r = (z & 1) ? 97 : 0;
        short* base = xnh + ((size_t)b * 98 + r) * 98 * 128;
        bf16x8 zero = {0,0,0,0,0,0,0,0};
        for (int i = t; i < 1568; i += 256)      // 1568*8 = 98*128
            ((bf16x8*)base)[i] = zero;
    } else if (bid < 784) {
        int z = bid - 776;
        int b = z / 2;
        int col = (z & 1) ? 97 : 0;
        bf16x8 zero = {0,0,0,0,0,0,0,0};
        for (int i = t; i < 1536; i += 256) {    // rows 1..96 x 16 c-groups
            int r  = 1 + i / 16;
            int c8 = i % 16;
            *(bf16x8*)(xnh + (((size_t)b * 98 + r) * 98 + col) * 128 + c8 * 8) = zero;
        }
    } else {
        int f = (bid - 784) * 256 + t;           // 0..36863
        int e    = f & 7;
        int l    = (f >> 3) & 63;
        int ch   = (f >> 9) & 3;
        int tap  = (f >> 11) % 9;
        int mt   = f / 18432;
        int oc = mt * 16 + (l & 15);
        int c  = ch * 32 + (l >> 4) * 8 + e;
        float v = (oc < NOC) ? rot_w[(size_t)oc * (Cdim * 9) + c * 9 + tap] : 0.f;
        wpk[f] = f2bf(v);
    }
}

// ---------------------------------------------------------------------------
// Kernel 2: conv (bf16 MFMA implicit GEMM) with FUSED coef epilogue.
// IDENTICAL to R7 (control).
// ---------------------------------------------------------------------------
__global__ __launch_bounds__(256, 2) void conv_mfma(const short* __restrict__ xnh,
                                                    const short* __restrict__ wpk,
                                                    const float* __restrict__ rot_b,
                                                    float4* __restrict__ coefq) {
    __shared__ short wlds[36864];                // 72 KB A-fragments
    __shared__ float dsc[64 * 20];               // 5 KB per-wave D scratch
    const int tid  = threadIdx.x;
    const int lane = tid & 63;
    const int wid  = tid >> 6;
    for (int i = tid; i < 4608; i += 256)
        ((bf16x8*)wlds)[i] = ((const bf16x8*)wpk)[i];
    __syncthreads();

    const int ntile = blockIdx.x * 4 + wid;      // 0..2303
    const int b   = ntile / 576;
    const int hw0 = (ntile % 576) * 16;
    const int h   = hw0 / Wdim;
    const int w0  = hw0 % Wdim;
    const int px = lane & 15, kg = lane >> 4;

    f32x4 a00 = {0,0,0,0}, a01 = {0,0,0,0};
    f32x4 a10 = {0,0,0,0}, a11 = {0,0,0,0};
    const short* xb = xnh + (((size_t)b * 98 + h) * 98 + (w0 + px)) * 128 + kg * 8;
    const short* wl = wlds + lane * 8;

    bf16x8 Bc[4], A0c[4], A1c[4];
#pragma unroll
    for (int ch = 0; ch < 4; ++ch) {             // preload tap 0
        Bc[ch]  = *(const bf16x8*)(xb + ch * 32);
        A0c[ch] = *(const bf16x8*)(wl + ch * 512);
        A1c[ch] = *(const bf16x8*)(wl + (36 + ch) * 512);
    }

#pragma unroll
    for (int tap = 0; tap < 9; ++tap) {
        bf16x8 Bn[4], A0n[4], A1n[4];
        if (tap < 8) {
            const int di = (tap + 1) / 3, dj = (tap + 1) % 3;
            const short* xr = xb + (di * 98 + dj) * 128;
#pragma unroll
            for (int ch = 0; ch < 4; ++ch) {
                Bn[ch]  = *(const bf16x8*)(xr + ch * 32);
                A0n[ch] = *(const bf16x8*)(wl + ((tap + 1) * 4 + ch) * 512);
                A1n[ch] = *(const bf16x8*)(wl + ((9 + tap + 1) * 4 + ch) * 512);
            }
        }
        a00 = __builtin_amdgcn_mfma_f32_16x16x32_bf16(A0c[0], Bc[0], a00, 0, 0, 0);
        a10 = __builtin_amdgcn_mfma_f32_16x16x32_bf16(A1c[0], Bc[0], a10, 0, 0, 0);
        a01 = __builtin_amdgcn_mfma_f32_16x16x32_bf16(A0c[1], Bc[1], a01, 0, 0, 0);
        a11 = __builtin_amdgcn_mfma_f32_16x16x32_bf16(A1c[1], Bc[1], a11, 0, 0, 0);
        a00 = __builtin_amdgcn_mfma_f32_16x16x32_bf16(A0c[2], Bc[2], a00, 0, 0, 0);
        a10 = __builtin_amdgcn_mfma_f32_16x16x32_bf16(A1c[2], Bc[2], a10, 0, 0, 0);
        a01 = __builtin_amdgcn_mfma_f32_16x16x32_bf16(A0c[3], Bc[3], a01, 0, 0, 0);
        a11 = __builtin_amdgcn_mfma_f32_16x16x32_bf16(A1c[3], Bc[3], a11, 0, 0, 0);
        if (tap < 8) {
#pragma unroll
            for (int ch = 0; ch < 4; ++ch) { Bc[ch] = Bn[ch]; A0c[ch] = A0n[ch]; A1c[ch] = A1n[ch]; }
        }
    }
    f32x4 acc0 = a00 + a01;
    f32x4 acc1 = a10 + a11;

    // ---- fused coef epilogue (per-wave, no barrier) ----
    float* ds = dsc + (wid * 16) * 20;
    *(f32x4*)(ds + px * 20 + kg * 4) = acc0;
    if (kg == 0) {
        ds[px * 20 + 16] = acc1[0];
        ds[px * 20 + 17] = acc1[1];
    }
    __builtin_amdgcn_wave_barrier();

    const int px2 = lane & 15, tq = lane >> 4;
    if (tq < 3) {
        const float* dr = ds + px2 * 20;
        const int hwp = hw0 + px2;
#pragma unroll
        for (int k = 0; k < 3; ++k) {
            int tt = tq * 3 + k;
            int i = tt / 3, j = tt % 3;
            float ch = dr[2 * tt]     + rot_b[2 * tt]     + (0.5f + (float)i);
            float cw = dr[2 * tt + 1] + rot_b[2 * tt + 1] + (0.5f + (float)j);
            ch = fminf(fmaxf(ch, 0.f), 3.f);
            cw = fminf(fmaxf(cw, 0.f), 3.f);
            float h0f = floorf(ch), w0f = floorf(cw);
            float lh = ch - h0f, lw = cw - w0f;
            int h0 = (int)h0f, w0i = (int)w0f;
            float bh0 = 1.f - lh;
            float aw0 = 1.f - lw;
            if (h0 >= 3)  { h0 = 2;  bh0 = 0.f; }
            if (w0i >= 3) { w0i = 2; aw0 = 0.f; }
            float4 cf;
            cf.x = aw0 * bh0;
            cf.y = (1.f - aw0) * bh0;
            cf.z = aw0 * (1.f - bh0);
            cf.w = (float)(h0 * 3 + w0i);
            coefq[(size_t)(b * 9 + tt) * HW + hwp] = cf;
        }
    }
}

// ---------------------------------------------------------------------------
// Kernel 3: apply. Thread = 1 pixel x 8 channels. grid (576,4), block (64,4).
// c0 = (blockIdx.y*4 + ty)*8. Live state ~70 VGPRs -> no spills, 7 waves/SIMD.
// Per tap: 1 dwordx4 xnh load + 1 coefq load (prefetched) + 8 ds_read_b64.
// ---------------------------------------------------------------------------
__global__ __launch_bounds__(256) void apply_kernel(const short* __restrict__ xnh,
                                                    const float4* __restrict__ coefq,
                                                    const float* __restrict__ weight,
                                                    float* __restrict__ out) {
    __shared__ ushort4 wq[Cdim * 9];             // [c][cell], 72B/c, 9216 B
    int tid = threadIdx.y * 64 + threadIdx.x;
    for (int i = tid; i < Cdim * 9; i += 256) {
        int c = i / 9, t = i - c * 9;
        int r = t / 3, s = t - r * 3;
        const float* wb = weight + (size_t)c * 16 + r * 4 + s;
        ushort4 u;
        u.x = __half_as_ushort(__float2half(wb[0]));
        u.y = __half_as_ushort(__float2half(wb[1]));
        u.z = __half_as_ushort(__float2half(wb[4]));
        u.w = __half_as_ushort(__float2half(wb[5]));
        wq[i] = u;
    }
    __syncthreads();

    int px = blockIdx.x * 64 + threadIdx.x;   // 0..36863
    int b  = px / HW;
    int hw = px % HW;
    int h  = hw / Wdim;
    int w  = hw % Wdim;

    float q00[9], q01[9], q10[9], q11[9];
    int lidx[9];
#pragma unroll
    for (int t = 0; t < 9; ++t) {
        float4 cf = coefq[(size_t)(b * 9 + t) * HW + hw];
        q00[t] = cf.x;
        q01[t] = cf.y;
        q10[t] = cf.z;
        q11[t] = 1.f - cf.x - cf.y - cf.z;
        lidx[t] = (int)cf.w;
    }

    const int c0 = (blockIdx.y * 4 + threadIdx.y) * 8;
    const short* xb = xnh + (((size_t)b * 98 + h) * 98 + w) * 128 + c0;

    float acc[8];
#pragma unroll
    for (int k = 0; k < 8; ++k) acc[k] = 0.f;

#pragma unroll
    for (int t = 0; t < 9; ++t) {
        const int di = t / 3, dj = t % 3;
        uint4 u = *(const uint4*)(xb + (di * 98 + dj) * 128);
        float xv[8];
        unpack8(u, xv);
        const ushort4* wrow = wq + c0 * 9 + lidx[t];
#pragma unroll
        for (int k = 0; k < 8; ++k) {
            ushort4 g = wrow[k * 9];             // wq[(c0+k)*9 + lidx[t]]
            float ws = q00[t] * __half2float(__ushort_as_half(g.x));
            ws = fmaf(q01[t], __half2float(__ushort_as_half(g.y)), ws);
            ws = fmaf(q10[t], __half2float(__ushort_as_half(g.z)), ws);
            ws = fmaf(q11[t], __half2float(__ushort_as_half(g.w)), ws);
            acc[k] = fmaf(ws, xv[k], acc[k]);
        }
    }

    float* ob = out + ((size_t)(b * Cdim + c0)) * HW + hw;
#pragma unroll
    for (int k = 0; k < 8; ++k)
        ob[(size_t)k * HW] = acc[k];
}

// ---------------------------------------------------------------------------
extern "C" void kernel_launch(void* const* d_in, const int* in_sizes, int n_in,
                              void* d_out, int out_size, void* d_ws, size_t ws_size,
                              hipStream_t stream) {
    const float* x      = (const float*)d_in[0];
    const float* rot_w  = (const float*)d_in[1];
    const float* rot_b  = (const float*)d_in[2];
    const float* weight = (const float*)d_in[3];
    float* out = (float*)d_out;

    char* ws = (char*)d_ws;
    const size_t xnh_bytes = (size_t)Bdim * 98 * 98 * 128 * 2;   // 9,834,496
    const size_t wpk_bytes = (size_t)2 * 9 * 4 * 64 * 8 * 2;     //    73,728

    short*  xnh   = (short*)ws;
    short*  wpk   = (short*)(ws + xnh_bytes);
    float4* coefq = (float4*)(ws + xnh_bytes + wpk_bytes);       // 5,308,416 B

    prep_kernel<<<928, 256, 0, stream>>>(x, rot_w, xnh, wpk);
    conv_mfma<<<576, 256, 0, stream>>>(xnh, wpk, rot_b, coefq);
    apply_kernel<<<dim3(Bdim * HW / 64, 4), dim3(64, 4), 0, stream>>>(xnh, coefq, weight, out);
}